// Round 1
// baseline (538.259 us; speedup 1.0000x reference)
//
#include <hip/hip_runtime.h>
#include <stdint.h>

typedef unsigned short u16;
typedef __bf16 bf16x8 __attribute__((ext_vector_type(8)));
typedef float f32x4 __attribute__((ext_vector_type(4)));

#define BATCH 16
#define NTOK 4096
#define DMODEL 384
#define NHEAD 8
#define DH 48
#define M_ROWS 65536   /* BATCH*NTOK */
#define QKVC 1152      /* 3*DMODEL */

static __device__ __forceinline__ float b2f(u16 u) {
    union { float f; unsigned int i; } x; x.i = ((unsigned int)u) << 16; return x.f;
}
static __device__ __forceinline__ u16 f2b(float f) {
    union { float f; unsigned int i; } x; x.f = f;
    unsigned int i = x.i;
    unsigned int r = (i + 0x7FFFu + ((i >> 16) & 1u)) >> 16;
    return (u16)r;
}

static __device__ __forceinline__ void gload_lds16(const void* g, void* l) {
    __builtin_amdgcn_global_load_lds(
        (const __attribute__((address_space(1))) void*)g,
        (__attribute__((address_space(3))) void*)l, 16, 0, 0);
}

// ---------------------------------------------------------------- fp32 -> bf16
__global__ __launch_bounds__(256) void cvt_f32_bf16(const float* __restrict__ src,
                                                    u16* __restrict__ dst, int n4) {
    int i = blockIdx.x * 256 + threadIdx.x;
    if (i < n4) {
        float4 v = ((const float4*)src)[i];
        ushort4 o;
        o.x = f2b(v.x); o.y = f2b(v.y); o.z = f2b(v.z); o.w = f2b(v.w);
        ((ushort4*)dst)[i] = o;
    }
}

// ------------------------------------------------- bf16 MFMA GEMM, C = A @ B^T + bias
// A: [M,K] bf16 row-major; B: [N,K] bf16 row-major; out bf16 or fp32.
// 128x128 tile, BK=32, 4 waves (2x2), each wave 64x64 = 4x4 frags of 16x16x32.
template<bool OUTF32>
__global__ __launch_bounds__(256) void gemm_bt(const u16* __restrict__ A,
                                               const u16* __restrict__ B,
                                               const float* __restrict__ bias,
                                               void* __restrict__ Cout,
                                               int M, int N, int K) {
    __shared__ u16 As[128 * 32];
    __shared__ u16 Bs[128 * 32];
    const int tid  = threadIdx.x;
    const int lane = tid & 63;
    const int wave = tid >> 6;
    const int wr = wave >> 1, wc = wave & 1;
    const int fr = lane & 15;             // frag row (A rows / B cols)
    const int fk = (lane >> 4) * 8;       // frag k offset
    const int m0 = blockIdx.y * 128, n0 = blockIdx.x * 128;
    const int ar = tid >> 2;              // staging row 0..63
    const int ak = (tid & 3) * 8;         // staging k 0,8,16,24

    f32x4 acc[4][4] = {};

    for (int kt = 0; kt < K; kt += 32) {
        gload_lds16(A + (size_t)(m0 + ar) * K + kt + ak,      As + tid * 8);
        gload_lds16(A + (size_t)(m0 + 64 + ar) * K + kt + ak, As + 2048 + tid * 8);
        gload_lds16(B + (size_t)(n0 + ar) * K + kt + ak,      Bs + tid * 8);
        gload_lds16(B + (size_t)(n0 + 64 + ar) * K + kt + ak, Bs + 2048 + tid * 8);
        __syncthreads();
        bf16x8 af[4], bfv[4];
        #pragma unroll
        for (int m = 0; m < 4; m++)
            af[m] = *(const bf16x8*)&As[(wr * 64 + m * 16 + fr) * 32 + fk];
        #pragma unroll
        for (int n = 0; n < 4; n++)
            bfv[n] = *(const bf16x8*)&Bs[(wc * 64 + n * 16 + fr) * 32 + fk];
        #pragma unroll
        for (int m = 0; m < 4; m++)
            #pragma unroll
            for (int n = 0; n < 4; n++)
                acc[m][n] = __builtin_amdgcn_mfma_f32_16x16x32_bf16(
                                af[m], bfv[n], acc[m][n], 0, 0, 0);
        __syncthreads();
    }
    // C/D layout: col = lane&15, row = (lane>>4)*4 + j   [m89/m91 verified]
    const int orow = (lane >> 4) * 4;
    const int ocol = lane & 15;
    #pragma unroll
    for (int m = 0; m < 4; m++) {
        #pragma unroll
        for (int n = 0; n < 4; n++) {
            int col = n0 + wc * 64 + n * 16 + ocol;
            float bv = bias[col];
            #pragma unroll
            for (int j = 0; j < 4; j++) {
                int row = m0 + wr * 64 + m * 16 + orow + j;
                float v = acc[m][n][j] + bv;
                if constexpr (OUTF32)
                    ((float*)Cout)[(size_t)row * N + col] = v;
                else
                    ((u16*)Cout)[(size_t)row * N + col] = f2b(v);
            }
        }
    }
}

// ---------------------------------- per-(batch,col) online max/sumexp partials
// Softmax is over the token axis (4096 rows within a batch) for q (cols 0..383)
// and k (cols 384..767) of the QKV matrix.
__global__ __launch_bounds__(256) void colstats(const u16* __restrict__ qkv,
                                                float2* __restrict__ part) {
    const int rc = blockIdx.x;   // 16 row-chunks of 256
    const int cc = blockIdx.y;   // 3 col-chunks of 256
    const int b  = blockIdx.z;   // 16
    const int col = cc * 256 + threadIdx.x;
    const u16* p = qkv + (size_t)(b * NTOK + rc * 256) * QKVC + col;
    float m = -1e30f, s = 0.f;
    for (int r = 0; r < 256; r++) {
        float v = b2f(p[(size_t)r * QKVC]);
        float nm = fmaxf(m, v);
        s = s * __expf(m - nm) + __expf(v - nm);
        m = nm;
    }
    part[(((size_t)b * 3 + cc) * 16 + rc) * 256 + threadIdx.x] = make_float2(m, s);
}

__global__ __launch_bounds__(256) void colstats_reduce(const float2* __restrict__ part,
                                                       float2* __restrict__ stats) {
    int idx = blockIdx.x * 256 + threadIdx.x;   // 16*768
    int b = idx / 768, col = idx % 768;
    int cc = col >> 8, t = col & 255;
    const float2* pp = part + (((size_t)b * 3 + cc) * 16) * 256 + t;
    float m = -1e30f;
    #pragma unroll
    for (int r = 0; r < 16; r++) m = fmaxf(m, pp[r * 256].x);
    float s = 0.f;
    #pragma unroll
    for (int r = 0; r < 16; r++) { float2 v = pp[r * 256]; s += v.y * __expf(v.x - m); }
    stats[idx] = make_float2(m, 1.0f / s);
}

// ------------------------------------------ KV = softmax(K)^T @ V  (48x48/head)
__global__ __launch_bounds__(256) void kv_accum(const u16* __restrict__ qkv,
                                                const float2* __restrict__ stats,
                                                float* __restrict__ kvout) {
    const int chunk = blockIdx.x;  // 4 chunks of 1024 tokens
    const int head  = blockIdx.y;  // 8
    const int b     = blockIdx.z;  // 16
    __shared__ float sk[128][48];
    __shared__ float vd[128][48];
    __shared__ float km[48], ki[48];
    const int tid = threadIdx.x;
    if (tid < 48) {
        float2 st = stats[b * 768 + 384 + head * 48 + tid];
        km[tid] = st.x; ki[tid] = st.y;
    }
    __syncthreads();
    float acc[3][3] = {};
    const int i0 = (tid >> 4) * 3;   // 16 groups x 3 rows of KV
    const int j0 = (tid & 15) * 3;   // 16 groups x 3 cols of KV
    const size_t rowbase = (size_t)(b * NTOK + chunk * 1024) * QKVC;
    for (int tile = 0; tile < 8; tile++) {
        const u16* kb = qkv + rowbase + (size_t)tile * 128 * QKVC + 384 + head * 48;
        const u16* vb = qkv + rowbase + (size_t)tile * 128 * QKVC + 768 + head * 48;
        for (int u = tid; u < 1536; u += 256) {      // 128 rows x 12 ushort4
            int t = u / 12, c4 = (u % 12) * 4;
            ushort4 kk = *(const ushort4*)(kb + (size_t)t * QKVC + c4);
            ushort4 vv = *(const ushort4*)(vb + (size_t)t * QKVC + c4);
            sk[t][c4 + 0] = __expf(b2f(kk.x) - km[c4 + 0]) * ki[c4 + 0];
            sk[t][c4 + 1] = __expf(b2f(kk.y) - km[c4 + 1]) * ki[c4 + 1];
            sk[t][c4 + 2] = __expf(b2f(kk.z) - km[c4 + 2]) * ki[c4 + 2];
            sk[t][c4 + 3] = __expf(b2f(kk.w) - km[c4 + 3]) * ki[c4 + 3];
            vd[t][c4 + 0] = b2f(vv.x); vd[t][c4 + 1] = b2f(vv.y);
            vd[t][c4 + 2] = b2f(vv.z); vd[t][c4 + 3] = b2f(vv.w);
        }
        __syncthreads();
        #pragma unroll 4
        for (int t = 0; t < 128; t++) {
            float a0 = sk[t][i0], a1 = sk[t][i0 + 1], a2 = sk[t][i0 + 2];
            float v0 = vd[t][j0], v1 = vd[t][j0 + 1], v2 = vd[t][j0 + 2];
            acc[0][0] += a0 * v0; acc[0][1] += a0 * v1; acc[0][2] += a0 * v2;
            acc[1][0] += a1 * v0; acc[1][1] += a1 * v1; acc[1][2] += a1 * v2;
            acc[2][0] += a2 * v0; acc[2][1] += a2 * v1; acc[2][2] += a2 * v2;
        }
        __syncthreads();
    }
    float* kp = kvout + (size_t)(b * NHEAD + head) * 2304;
    #pragma unroll
    for (int ii = 0; ii < 3; ii++)
        #pragma unroll
        for (int jj = 0; jj < 3; jj++)
            atomicAdd(&kp[(i0 + ii) * 48 + (j0 + jj)], acc[ii][jj]);
}

// ------------- attn = (softq @ KV) / (rowsum(softq) + eps), merged-head layout
__global__ __launch_bounds__(256) void attn_kernel(const u16* __restrict__ qkv,
                                                   const float2* __restrict__ stats,
                                                   const float* __restrict__ kv,
                                                   u16* __restrict__ attnb) {
    const int tc   = blockIdx.x;  // 16 token-chunks of 256
    const int head = blockIdx.y;
    const int b    = blockIdx.z;
    __shared__ float KVs[48][48];
    __shared__ u16 qt[256][50];   // +2 pad -> 100B row stride, bank-spread
    __shared__ float qm[48], qi[48];
    const int tid = threadIdx.x;
    if (tid < 48) {
        float2 st = stats[b * 768 + head * 48 + tid];
        qm[tid] = st.x; qi[tid] = st.y;
    }
    {
        const float* kp = kv + (size_t)(b * NHEAD + head) * 2304;
        for (int u = tid; u < 2304; u += 256) KVs[u / 48][u % 48] = kp[u];
    }
    const size_t rowbase = (size_t)(b * NTOK + tc * 256) * QKVC + head * 48;
    for (int u = tid; u < 6144; u += 256) {   // 256 rows x 24 ushort2
        int t = u / 24, c2 = (u % 24) * 2;
        *(ushort2*)&qt[t][c2] = *(const ushort2*)(qkv + rowbase + (size_t)t * QKVC + c2);
    }
    __syncthreads();
    float sq[48];
    float den = 1e-7f;   // EPS
    #pragma unroll
    for (int c = 0; c < 48; c++) {
        float s = __expf(b2f(qt[tid][c]) - qm[c]) * qi[c];
        sq[c] = s; den += s;
    }
    float rden = 1.0f / den;
    #pragma unroll 4
    for (int j4 = 0; j4 < 12; j4++) {
        f32x4 s = {0.f, 0.f, 0.f, 0.f};
        #pragma unroll
        for (int i = 0; i < 48; i++) {
            f32x4 kvrow = *(const f32x4*)&KVs[i][j4 * 4];
            s += sq[i] * kvrow;
        }
        qt[tid][j4 * 4 + 0] = f2b(s[0] * rden);
        qt[tid][j4 * 4 + 1] = f2b(s[1] * rden);
        qt[tid][j4 * 4 + 2] = f2b(s[2] * rden);
        qt[tid][j4 * 4 + 3] = f2b(s[3] * rden);
    }
    __syncthreads();
    u16* ob = attnb + (size_t)(b * NTOK + tc * 256) * DMODEL + head * 48;
    for (int u = tid; u < 6144; u += 256) {
        int t = u / 24, c2 = (u % 24) * 2;
        *(ushort2*)(ob + (size_t)t * DMODEL + c2) = *(const ushort2*)&qt[t][c2];
    }
}

// -----------------------------------------------------------------------------
extern "C" void kernel_launch(void* const* d_in, const int* in_sizes, int n_in,
                              void* d_out, int out_size, void* d_ws, size_t ws_size,
                              hipStream_t stream) {
    const float* x     = (const float*)d_in[0];
    const float* wqkv  = (const float*)d_in[1];
    const float* bqkv  = (const float*)d_in[2];
    const float* wproj = (const float*)d_in[3];
    const float* bproj = (const float*)d_in[4];

    char* ws = (char*)d_ws;
    size_t off = 0;
    auto take = [&](size_t bytes) {
        char* p = ws + off;
        off = (off + bytes + 255) & ~(size_t)255;
        return p;
    };
    u16*    xb    = (u16*)take((size_t)M_ROWS * DMODEL * 2);   // also reused as attn buffer
    u16*    wqb   = (u16*)take((size_t)QKVC * DMODEL * 2);
    u16*    wpb   = (u16*)take((size_t)DMODEL * DMODEL * 2);
    u16*    qkvb  = (u16*)take((size_t)M_ROWS * QKVC * 2);
    float2* stats = (float2*)take((size_t)BATCH * 768 * sizeof(float2));
    float2* part  = (float2*)take((size_t)BATCH * 3 * 16 * 256 * sizeof(float2));
    float*  kv    = (float*)take((size_t)BATCH * NHEAD * DH * DH * sizeof(float));
    u16*    attnb = xb;   // xb is dead after GEMM1; alias saves 50 MB

    // fp32 -> bf16
    cvt_f32_bf16<<<dim3(M_ROWS * DMODEL / 4 / 256), 256, 0, stream>>>(x, xb, M_ROWS * DMODEL / 4);
    cvt_f32_bf16<<<dim3(QKVC * DMODEL / 4 / 256), 256, 0, stream>>>(wqkv, wqb, QKVC * DMODEL / 4);
    cvt_f32_bf16<<<dim3(DMODEL * DMODEL / 4 / 256), 256, 0, stream>>>(wproj, wpb, DMODEL * DMODEL / 4);

    // QKV = x @ w_qkv^T + b_qkv   [65536 x 1152] bf16
    gemm_bt<false><<<dim3(QKVC / 128, M_ROWS / 128), 256, 0, stream>>>(
        xb, wqb, bqkv, qkvb, M_ROWS, QKVC, DMODEL);

    // token-axis softmax stats for q and k columns
    colstats<<<dim3(16, 3, BATCH), 256, 0, stream>>>(qkvb, part);
    colstats_reduce<<<dim3(BATCH * 768 / 256), 256, 0, stream>>>(part, stats);

    // KV = softk^T @ v per (b, head)
    hipMemsetAsync(kv, 0, (size_t)BATCH * NHEAD * DH * DH * sizeof(float), stream);
    kv_accum<<<dim3(4, NHEAD, BATCH), 256, 0, stream>>>(qkvb, stats, kv);

    // attn = (softq @ KV) / (rowsum(softq) + eps), merged heads -> [65536 x 384] bf16
    attn_kernel<<<dim3(16, NHEAD, BATCH), 256, 0, stream>>>(qkvb, stats, kv, attnb);

    // out = attn @ w_proj^T + b_proj   fp32
    gemm_bt<true><<<dim3(DMODEL / 128, M_ROWS / 128), 256, 0, stream>>>(
        attnb, wpb, bproj, d_out, M_ROWS, DMODEL, DMODEL);
}

// Round 2
// 426.989 us; speedup vs baseline: 1.2606x; 1.2606x over previous
//
#include <hip/hip_runtime.h>
#include <stdint.h>

typedef unsigned short u16;
typedef __bf16 bf16x8 __attribute__((ext_vector_type(8)));
typedef unsigned short u16x8 __attribute__((ext_vector_type(8)));
typedef float f32x4 __attribute__((ext_vector_type(4)));

#define BATCH 16
#define NTOK 4096
#define DMODEL 384
#define NHEAD 8
#define DH 48
#define M_ROWS 65536   /* BATCH*NTOK */
#define QKVC 1152      /* 3*DMODEL */

static __device__ __forceinline__ float b2f(u16 u) {
    union { float f; unsigned int i; } x; x.i = ((unsigned int)u) << 16; return x.f;
}
static __device__ __forceinline__ u16 f2b(float f) {
    union { float f; unsigned int i; } x; x.f = f;
    unsigned int i = x.i;
    unsigned int r = (i + 0x7FFFu + ((i >> 16) & 1u)) >> 16;
    return (u16)r;
}

static __device__ __forceinline__ void gload_lds16(const void* g, void* l) {
    __builtin_amdgcn_global_load_lds(
        (const __attribute__((address_space(1))) void*)g,
        (__attribute__((address_space(3))) void*)l, 16, 0, 0);
}

// ---------------------------------------------------------------- fp32 -> bf16
__global__ __launch_bounds__(256) void cvt_f32_bf16(const float* __restrict__ src,
                                                    u16* __restrict__ dst, int n4) {
    int i = blockIdx.x * 256 + threadIdx.x;
    if (i < n4) {
        float4 v = ((const float4*)src)[i];
        ushort4 o;
        o.x = f2b(v.x); o.y = f2b(v.y); o.z = f2b(v.z); o.w = f2b(v.w);
        ((ushort4*)dst)[i] = o;
    }
}

// ------------------------------------------------- bf16 MFMA GEMM, C = A @ B^T + bias
// A: [M,K] bf16 row-major; B: [N,K] bf16 row-major; out bf16 or fp32.
// 128x128 tile, BK=32, 4 waves (2x2), each wave 64x64 = 4x4 frags of 16x16x32.
template<bool OUTF32>
__global__ __launch_bounds__(256) void gemm_bt(const u16* __restrict__ A,
                                               const u16* __restrict__ B,
                                               const float* __restrict__ bias,
                                               void* __restrict__ Cout,
                                               int M, int N, int K) {
    __shared__ u16 As[128 * 32];
    __shared__ u16 Bs[128 * 32];
    const int tid  = threadIdx.x;
    const int lane = tid & 63;
    const int wave = tid >> 6;
    const int wr = wave >> 1, wc = wave & 1;
    const int fr = lane & 15;             // frag row (A rows / B cols)
    const int fk = (lane >> 4) * 8;       // frag k offset
    const int m0 = blockIdx.y * 128, n0 = blockIdx.x * 128;
    const int ar = tid >> 2;              // staging row 0..63
    const int ak = (tid & 3) * 8;         // staging k 0,8,16,24

    f32x4 acc[4][4] = {};

    for (int kt = 0; kt < K; kt += 32) {
        gload_lds16(A + (size_t)(m0 + ar) * K + kt + ak,      As + tid * 8);
        gload_lds16(A + (size_t)(m0 + 64 + ar) * K + kt + ak, As + 2048 + tid * 8);
        gload_lds16(B + (size_t)(n0 + ar) * K + kt + ak,      Bs + tid * 8);
        gload_lds16(B + (size_t)(n0 + 64 + ar) * K + kt + ak, Bs + 2048 + tid * 8);
        __syncthreads();
        bf16x8 af[4], bfv[4];
        #pragma unroll
        for (int m = 0; m < 4; m++)
            af[m] = *(const bf16x8*)&As[(wr * 64 + m * 16 + fr) * 32 + fk];
        #pragma unroll
        for (int n = 0; n < 4; n++)
            bfv[n] = *(const bf16x8*)&Bs[(wc * 64 + n * 16 + fr) * 32 + fk];
        #pragma unroll
        for (int m = 0; m < 4; m++)
            #pragma unroll
            for (int n = 0; n < 4; n++)
                acc[m][n] = __builtin_amdgcn_mfma_f32_16x16x32_bf16(
                                af[m], bfv[n], acc[m][n], 0, 0, 0);
        __syncthreads();
    }
    const int orow = (lane >> 4) * 4;
    const int ocol = lane & 15;
    #pragma unroll
    for (int m = 0; m < 4; m++) {
        #pragma unroll
        for (int n = 0; n < 4; n++) {
            int col = n0 + wc * 64 + n * 16 + ocol;
            float bv = bias[col];
            #pragma unroll
            for (int j = 0; j < 4; j++) {
                int row = m0 + wr * 64 + m * 16 + orow + j;
                float v = acc[m][n][j] + bv;
                if constexpr (OUTF32)
                    ((float*)Cout)[(size_t)row * N + col] = v;
                else
                    ((u16*)Cout)[(size_t)row * N + col] = f2b(v);
            }
        }
    }
}

// ---------------------------------- per-(batch,col) online max/sumexp partials
// 4 independent online chains to break the serial exp dependency.
__global__ __launch_bounds__(256) void colstats(const u16* __restrict__ qkv,
                                                float2* __restrict__ part) {
    const int rc = blockIdx.x;   // 16 row-chunks of 256
    const int cc = blockIdx.y;   // 3 col-chunks of 256
    const int b  = blockIdx.z;   // 16
    const int col = cc * 256 + threadIdx.x;
    const u16* p = qkv + (size_t)(b * NTOK + rc * 256) * QKVC + col;
    float m0 = -1e30f, m1 = -1e30f, m2 = -1e30f, m3 = -1e30f;
    float s0 = 0.f, s1 = 0.f, s2 = 0.f, s3 = 0.f;
    for (int r = 0; r < 256; r += 4) {
        float v0 = b2f(p[(size_t)(r + 0) * QKVC]);
        float v1 = b2f(p[(size_t)(r + 1) * QKVC]);
        float v2 = b2f(p[(size_t)(r + 2) * QKVC]);
        float v3 = b2f(p[(size_t)(r + 3) * QKVC]);
        float n0 = fmaxf(m0, v0); s0 = s0 * __expf(m0 - n0) + __expf(v0 - n0); m0 = n0;
        float n1 = fmaxf(m1, v1); s1 = s1 * __expf(m1 - n1) + __expf(v1 - n1); m1 = n1;
        float n2 = fmaxf(m2, v2); s2 = s2 * __expf(m2 - n2) + __expf(v2 - n2); m2 = n2;
        float n3 = fmaxf(m3, v3); s3 = s3 * __expf(m3 - n3) + __expf(v3 - n3); m3 = n3;
    }
    float m = fmaxf(fmaxf(m0, m1), fmaxf(m2, m3));
    float s = s0 * __expf(m0 - m) + s1 * __expf(m1 - m)
            + s2 * __expf(m2 - m) + s3 * __expf(m3 - m);
    part[(((size_t)b * 3 + cc) * 16 + rc) * 256 + threadIdx.x] = make_float2(m, s);
}

__global__ __launch_bounds__(256) void colstats_reduce(const float2* __restrict__ part,
                                                       float2* __restrict__ stats) {
    int idx = blockIdx.x * 256 + threadIdx.x;   // 16*768
    int b = idx / 768, col = idx % 768;
    int cc = col >> 8, t = col & 255;
    const float2* pp = part + (((size_t)b * 3 + cc) * 16) * 256 + t;
    float m = -1e30f;
    #pragma unroll
    for (int r = 0; r < 16; r++) m = fmaxf(m, pp[r * 256].x);
    float s = 0.f;
    #pragma unroll
    for (int r = 0; r < 16; r++) { float2 v = pp[r * 256]; s += v.y * __expf(v.x - m); }
    stats[idx] = make_float2(m, 1.0f / s);
}

// --------------------- KV^T accumulation via MFMA: D[j][i] = sum_t v[t][j]*softk[t][i]
// LDS: ckv[ch][128 tokens] bf16, ch 0..47 = softk, 48..95 = v; XOR-swizzled 16B granules.
__global__ __launch_bounds__(256) void kv_accum_mfma(const u16* __restrict__ qkv,
                                                     const float2* __restrict__ stats,
                                                     float* __restrict__ kvt) {
    const int tc = blockIdx.x;   // 8 chunks of 512 tokens
    const int h  = blockIdx.y;   // 8
    const int b  = blockIdx.z;   // 16
    __shared__ char ckv[96 * 256];
    __shared__ float km[48], ki[48];
    const int tid  = threadIdx.x;
    const int lane = tid & 63, wave = tid >> 6;
    const int fr = lane & 15, kg = lane >> 4;
    if (tid < 48) {
        float2 st = stats[b * 768 + 384 + h * 48 + tid];
        km[tid] = st.x; ki[tid] = st.y;
    }
    __syncthreads();
    f32x4 acc[3][3] = {};
    const size_t rowbase = (size_t)(b * NTOK + tc * 512);
    for (int iter = 0; iter < 4; iter++) {
        const size_t tbase = rowbase + iter * 128;
        // stage 128 tokens x 96 ch, transposed + swizzled, pair-packed writes
        for (int u = tid; u < 1536; u += 256) {
            int p = u / 24, c4 = u % 24;
            int t = p * 2;
            int kpart = (c4 < 12);
            int lch = kpart ? c4 * 4 : (c4 - 12) * 4;       // 0..44
            int ch  = kpart ? lch : (48 + lch);
            int gch = kpart ? (384 + h * 48 + lch) : (768 + h * 48 + lch);
            const u16* r0 = qkv + (tbase + t) * QKVC + gch;
            ushort4 a  = *(const ushort4*)r0;
            ushort4 bb = *(const ushort4*)(r0 + QKVC);
            #pragma unroll
            for (int e = 0; e < 4; e++) {
                u16 ae = ((const u16*)&a)[e], be = ((const u16*)&bb)[e];
                u16 lo, hi;
                if (kpart) {
                    float mm = km[lch + e], si = ki[lch + e];
                    lo = f2b(__expf(b2f(ae) - mm) * si);
                    hi = f2b(__expf(b2f(be) - mm) * si);
                } else { lo = ae; hi = be; }
                int che = ch + e;
                int byteoff = che * 256 + ((((t >> 3) ^ (che & 15)) << 4)) + ((t & 7) * 2);
                *(unsigned int*)(ckv + byteoff) = (unsigned int)lo | ((unsigned int)hi << 16);
            }
        }
        __syncthreads();
        // wave w consumes its 32 tokens (K-split)
        const int g0 = wave * 4;  // granule base (tokens/8)
        bf16x8 afv[3], bfk[3];
        #pragma unroll
        for (int mt = 0; mt < 3; mt++) {
            int chv = 48 + mt * 16 + fr;
            afv[mt] = *(const bf16x8*)(ckv + chv * 256 + (((g0 + kg) ^ (chv & 15)) << 4));
            int chk = mt * 16 + fr;
            bfk[mt] = *(const bf16x8*)(ckv + chk * 256 + (((g0 + kg) ^ (chk & 15)) << 4));
        }
        #pragma unroll
        for (int mt = 0; mt < 3; mt++)
            #pragma unroll
            for (int nt = 0; nt < 3; nt++)
                acc[mt][nt] = __builtin_amdgcn_mfma_f32_16x16x32_bf16(
                                  afv[mt], bfk[nt], acc[mt][nt], 0, 0, 0);
        __syncthreads();
    }
    float* kp = kvt + (size_t)(b * NHEAD + h) * 2304;
    const int orow = kg * 4, ocol = fr;
    #pragma unroll
    for (int mt = 0; mt < 3; mt++)
        #pragma unroll
        for (int nt = 0; nt < 3; nt++)
            #pragma unroll
            for (int j = 0; j < 4; j++)
                atomicAdd(&kp[(mt * 16 + orow + j) * 48 + nt * 16 + ocol], acc[mt][nt][j]);
}

// ----------------------------- KV^T f32 [g][48][48] -> bf16 [g][48][64] zero-padded
__global__ __launch_bounds__(256) void kvt_to_bf16(const float* __restrict__ kvt,
                                                   u16* __restrict__ kvtb) {
    int idx = blockIdx.x * 256 + threadIdx.x;   // 128*48*64
    int g  = idx / 3072;
    int r  = (idx >> 6) % 48;
    int ii = idx & 63;
    float v = (ii < 48) ? kvt[(size_t)g * 2304 + r * 48 + ii] : 0.f;
    kvtb[idx] = f2b(v);
}

// ---------------- attn = (softq @ KV) / (rowsum(softq)+eps) via MFMA, per (tc,h,b)
__global__ __launch_bounds__(256) void attn_mfma(const u16* __restrict__ qkv,
                                                 const float2* __restrict__ stats,
                                                 const u16* __restrict__ kvtb,
                                                 u16* __restrict__ attnb) {
    const int tc = blockIdx.x;  // 16 chunks of 256 tokens
    const int h  = blockIdx.y;
    const int b  = blockIdx.z;
    __shared__ u16 obuf[256][50];
    const int tid  = threadIdx.x;
    const int lane = tid & 63, wave = tid >> 6;
    const int fr = lane & 15, kg = lane >> 4;
    const int g = b * NHEAD + h;

    // B-frags: KV[k][jout] = kvtb[g][jout][k], k padded to 64
    bf16x8 bf[3][2];
    #pragma unroll
    for (int nt = 0; nt < 3; nt++)
        #pragma unroll
        for (int kt = 0; kt < 2; kt++)
            bf[nt][kt] = *(const bf16x8*)(kvtb + (size_t)g * 3072 + (nt * 16 + fr) * 64
                                          + kt * 32 + kg * 8);
    // per-lane q softmax stats for its 8 channels per ktile
    float qm8[2][8], qi8[2][8];
    #pragma unroll
    for (int kt = 0; kt < 2; kt++) {
        int ch0 = kt * 32 + kg * 8;
        if (ch0 < 48) {
            #pragma unroll
            for (int e = 0; e < 8; e++) {
                float2 st = stats[b * 768 + h * 48 + ch0 + e];
                qm8[kt][e] = st.x; qi8[kt][e] = st.y;
            }
        }
    }

    f32x4 acc[4][3] = {};
    float den4[4];
    const size_t qbase = ((size_t)(b * NTOK + tc * 256 + wave * 64)) * QKVC + h * 48;
    #pragma unroll
    for (int m = 0; m < 4; m++) {
        const u16* qrow = qkv + qbase + (size_t)(m * 16 + fr) * QKVC;
        float denp = 0.f;
        bf16x8 af[2];
        #pragma unroll
        for (int kt = 0; kt < 2; kt++) {
            int ch0 = kt * 32 + kg * 8;
            u16x8 av = {};
            if (ch0 < 48) {
                ushort4 a0 = *(const ushort4*)(qrow + ch0);
                ushort4 a1 = *(const ushort4*)(qrow + ch0 + 4);
                #pragma unroll
                for (int e = 0; e < 8; e++) {
                    u16 qv = (e < 4) ? ((const u16*)&a0)[e] : ((const u16*)&a1)[e - 4];
                    float s = __expf(b2f(qv) - qm8[kt][e]) * qi8[kt][e];
                    denp += s;
                    av[e] = f2b(s);
                }
            }
            union { u16x8 u; bf16x8 b; } cvt; cvt.u = av;
            af[kt] = cvt.b;
        }
        denp += __shfl_xor(denp, 16);
        denp += __shfl_xor(denp, 32);
        den4[m] = denp + 1e-7f;   // EPS
        #pragma unroll
        for (int nt = 0; nt < 3; nt++)
            #pragma unroll
            for (int kt = 0; kt < 2; kt++)
                acc[m][nt] = __builtin_amdgcn_mfma_f32_16x16x32_bf16(
                                 af[kt], bf[nt][kt], acc[m][nt], 0, 0, 0);
    }
    const int orow = kg * 4, ocol = fr;
    #pragma unroll
    for (int m = 0; m < 4; m++) {
        float rd[4];
        #pragma unroll
        for (int j = 0; j < 4; j++)
            rd[j] = 1.0f / __shfl(den4[m], orow + j);
        #pragma unroll
        for (int nt = 0; nt < 3; nt++)
            #pragma unroll
            for (int j = 0; j < 4; j++)
                obuf[wave * 64 + m * 16 + orow + j][nt * 16 + ocol] =
                    f2b(acc[m][nt][j] * rd[j]);
    }
    __syncthreads();
    u16* ob = attnb + ((size_t)(b * NTOK + tc * 256)) * DMODEL + h * 48;
    for (int u = tid; u < 6144; u += 256) {
        int t = u / 24, c2 = (u % 24) * 2;
        *(ushort2*)(ob + (size_t)t * DMODEL + c2) = *(const ushort2*)&obuf[t][c2];
    }
}

// -----------------------------------------------------------------------------
extern "C" void kernel_launch(void* const* d_in, const int* in_sizes, int n_in,
                              void* d_out, int out_size, void* d_ws, size_t ws_size,
                              hipStream_t stream) {
    const float* x     = (const float*)d_in[0];
    const float* wqkv  = (const float*)d_in[1];
    const float* bqkv  = (const float*)d_in[2];
    const float* wproj = (const float*)d_in[3];
    const float* bproj = (const float*)d_in[4];

    char* ws = (char*)d_ws;
    size_t off = 0;
    auto take = [&](size_t bytes) {
        char* p = ws + off;
        off = (off + bytes + 255) & ~(size_t)255;
        return p;
    };
    u16*    xb    = (u16*)take((size_t)M_ROWS * DMODEL * 2);
    u16*    wqb   = (u16*)take((size_t)QKVC * DMODEL * 2);
    u16*    wpb   = (u16*)take((size_t)DMODEL * DMODEL * 2);
    u16*    qkvb  = (u16*)take((size_t)M_ROWS * QKVC * 2);
    float2* stats = (float2*)take((size_t)BATCH * 768 * sizeof(float2));
    float2* part  = (float2*)take((size_t)BATCH * 3 * 16 * 256 * sizeof(float2));
    float*  kvt   = (float*)take((size_t)BATCH * NHEAD * DH * DH * sizeof(float));
    u16*    kvtb  = (u16*)take((size_t)BATCH * NHEAD * DH * 64 * 2);
    u16*    attnb = xb;   // xb dead after GEMM1

    cvt_f32_bf16<<<dim3(M_ROWS * DMODEL / 4 / 256), 256, 0, stream>>>(x, xb, M_ROWS * DMODEL / 4);
    cvt_f32_bf16<<<dim3(QKVC * DMODEL / 4 / 256), 256, 0, stream>>>(wqkv, wqb, QKVC * DMODEL / 4);
    cvt_f32_bf16<<<dim3(DMODEL * DMODEL / 4 / 256), 256, 0, stream>>>(wproj, wpb, DMODEL * DMODEL / 4);

    // QKV = x @ w_qkv^T + b_qkv
    gemm_bt<false><<<dim3(QKVC / 128, M_ROWS / 128), 256, 0, stream>>>(
        xb, wqb, bqkv, qkvb, M_ROWS, QKVC, DMODEL);

    // token-axis softmax stats for q,k columns
    colstats<<<dim3(16, 3, BATCH), 256, 0, stream>>>(qkvb, part);
    colstats_reduce<<<dim3(BATCH * 768 / 256), 256, 0, stream>>>(part, stats);

    // KV^T accumulate (f32 atomics) then convert to padded bf16
    hipMemsetAsync(kvt, 0, (size_t)BATCH * NHEAD * DH * DH * sizeof(float), stream);
    kv_accum_mfma<<<dim3(NTOK / 512, NHEAD, BATCH), 256, 0, stream>>>(qkvb, stats, kvt);
    kvt_to_bf16<<<dim3(BATCH * NHEAD * DH * 64 / 256), 256, 0, stream>>>(kvt, kvtb);

    // attn = (softq @ KV) / denom, merged heads
    attn_mfma<<<dim3(16, NHEAD, BATCH), 256, 0, stream>>>(qkvb, stats, kvtb, attnb);

    // out = attn @ w_proj^T + b_proj
    gemm_bt<true><<<dim3(DMODEL / 128, M_ROWS / 128), 256, 0, stream>>>(
        attnb, wpb, bproj, d_out, M_ROWS, DMODEL, DMODEL);
}

// Round 3
// 400.272 us; speedup vs baseline: 1.3447x; 1.0667x over previous
//
#include <hip/hip_runtime.h>
#include <stdint.h>

typedef unsigned short u16;
typedef __bf16 bf16x8 __attribute__((ext_vector_type(8)));
typedef unsigned short u16x8 __attribute__((ext_vector_type(8)));
typedef float f32x4 __attribute__((ext_vector_type(4)));

#define BATCH 16
#define NTOK 4096
#define DMODEL 384
#define NHEAD 8
#define DH 48
#define M_ROWS 65536   /* BATCH*NTOK */
#define QKVC 1152      /* 3*DMODEL */
#define HPANE (NTOK * DH)   /* 196608 elements per (b,which,head) panel */

static __device__ __forceinline__ float b2f(u16 u) {
    union { float f; unsigned int i; } x; x.i = ((unsigned int)u) << 16; return x.f;
}
static __device__ __forceinline__ u16 f2b(float f) {
    union { float f; unsigned int i; } x; x.f = f;
    unsigned int i = x.i;
    unsigned int r = (i + 0x7FFFu + ((i >> 16) & 1u)) >> 16;
    return (u16)r;
}

static __device__ __forceinline__ void gload_lds16(const void* g, void* l) {
    __builtin_amdgcn_global_load_lds(
        (const __attribute__((address_space(1))) void*)g,
        (__attribute__((address_space(3))) void*)l, 16, 0, 0);
}

// ---------------------------------------------------------------- fp32 -> bf16
__global__ __launch_bounds__(256) void cvt_f32_bf16(const float* __restrict__ src,
                                                    u16* __restrict__ dst, int n4) {
    int i = blockIdx.x * 256 + threadIdx.x;
    if (i < n4) {
        float4 v = ((const float4*)src)[i];
        ushort4 o;
        o.x = f2b(v.x); o.y = f2b(v.y); o.z = f2b(v.z); o.w = f2b(v.w);
        ((ushort4*)dst)[i] = o;
    }
}

// ------------------------------------------------- bf16 MFMA GEMM, C = A @ B^T + bias
// A: [M,K] bf16 row-major; B: [N,K] bf16 row-major.
// QKV=false: Cout row-major [M,N] (f32 if OUTF32 else bf16).
// QKV=true : Cout = u16 qkv in [b][which][head][tok][48] panels, plus per-column
//            sum-of-exp atomics into statsOut[b*768+col] for cols < 768.
// 128x128 tile, BK=32, 4 waves (2x2). XCD-bijective block swizzle (m204).
template<bool OUTF32, bool QKV>
__global__ __launch_bounds__(256) void gemm_bt(const u16* __restrict__ A,
                                               const u16* __restrict__ B,
                                               const float* __restrict__ bias,
                                               void* __restrict__ Cout,
                                               float* __restrict__ statsOut,
                                               int M, int N, int K) {
    __shared__ u16 As[128 * 32];
    __shared__ u16 Bs[128 * 32];
    const int tid  = threadIdx.x;
    const int lane = tid & 63;
    const int wave = tid >> 6;
    const int wr = wave >> 1, wc = wave & 1;
    const int fr = lane & 15;
    const int fk = (lane >> 4) * 8;

    // XCD-aware bijective swizzle: each XCD gets a contiguous chunk of wgids
    const int nwg  = gridDim.x * gridDim.y;
    const int orig = blockIdx.y * gridDim.x + blockIdx.x;
    const int qq = nwg >> 3, rr = nwg & 7;
    const int xcd = orig & 7, ii = orig >> 3;
    const int wgid = (xcd < rr ? xcd * (qq + 1) : rr * (qq + 1) + (xcd - rr) * qq) + ii;
    const int m0 = (wgid / gridDim.x) * 128;
    const int n0 = (wgid % gridDim.x) * 128;

    const int ar = tid >> 2;
    const int ak = (tid & 3) * 8;

    f32x4 acc[4][4] = {};

    for (int kt = 0; kt < K; kt += 32) {
        gload_lds16(A + (size_t)(m0 + ar) * K + kt + ak,      As + tid * 8);
        gload_lds16(A + (size_t)(m0 + 64 + ar) * K + kt + ak, As + 2048 + tid * 8);
        gload_lds16(B + (size_t)(n0 + ar) * K + kt + ak,      Bs + tid * 8);
        gload_lds16(B + (size_t)(n0 + 64 + ar) * K + kt + ak, Bs + 2048 + tid * 8);
        __syncthreads();
        bf16x8 af[4], bfv[4];
        #pragma unroll
        for (int m = 0; m < 4; m++)
            af[m] = *(const bf16x8*)&As[(wr * 64 + m * 16 + fr) * 32 + fk];
        #pragma unroll
        for (int n = 0; n < 4; n++)
            bfv[n] = *(const bf16x8*)&Bs[(wc * 64 + n * 16 + fr) * 32 + fk];
        #pragma unroll
        for (int m = 0; m < 4; m++)
            #pragma unroll
            for (int n = 0; n < 4; n++)
                acc[m][n] = __builtin_amdgcn_mfma_f32_16x16x32_bf16(
                                af[m], bfv[n], acc[m][n], 0, 0, 0);
        __syncthreads();
    }
    const int orow = (lane >> 4) * 4;
    const int ocol = lane & 15;

    if constexpr (QKV) {
        const int bb   = m0 >> 12;               // batch (128 | 4096)
        const int tok0 = (m0 & 4095) + wr * 64 + orow;
        float colsum[4] = {0.f, 0.f, 0.f, 0.f};
        #pragma unroll
        for (int n = 0; n < 4; n++) {
            const int cbase = n0 + wc * 64 + n * 16;
            const int which = cbase / 384;
            const int hh  = (cbase - which * 384) / 48;
            const int dh0 = cbase - which * 384 - hh * 48;
            u16* dst = (u16*)Cout + ((size_t)((bb * 3 + which) * 8 + hh)) * HPANE
                       + dh0 + ocol;
            const float bv = bias[cbase + ocol];
            const bool qk = (cbase < 768);
            #pragma unroll
            for (int m = 0; m < 4; m++) {
                #pragma unroll
                for (int j = 0; j < 4; j++) {
                    float v = acc[m][n][j] + bv;
                    u16 vb = f2b(v);
                    dst[(size_t)(tok0 + m * 16 + j) * 48] = vb;
                    if (qk) colsum[n] += __expf(b2f(vb));
                }
            }
        }
        #pragma unroll
        for (int n = 0; n < 4; n++) {
            const int cbase = n0 + wc * 64 + n * 16;
            if (cbase < 768) {
                float s = colsum[n];
                s += __shfl_xor(s, 16);
                s += __shfl_xor(s, 32);
                if (lane < 16)
                    atomicAdd(&statsOut[bb * 768 + cbase + ocol], s);
            }
        }
    } else {
        #pragma unroll
        for (int m = 0; m < 4; m++) {
            #pragma unroll
            for (int n = 0; n < 4; n++) {
                int col = n0 + wc * 64 + n * 16 + ocol;
                float bv = bias[col];
                #pragma unroll
                for (int j = 0; j < 4; j++) {
                    int row = m0 + wr * 64 + m * 16 + orow + j;
                    float v = acc[m][n][j] + bv;
                    if constexpr (OUTF32)
                        ((float*)Cout)[(size_t)row * N + col] = v;
                    else
                        ((u16*)Cout)[(size_t)row * N + col] = f2b(v);
                }
            }
        }
    }
}

// --------------------- KV^T accumulation via MFMA: D[j][i] = sum_t v[t][j]*softk[t][i]
// qkv in head-panel layout; k,v panels are dense [4096][48] per (b,h).
// LDS: ckv[ch][128 tokens] bf16, ch 0..47 = softk, 48..95 = v; XOR-swizzled 16B granules.
__global__ __launch_bounds__(256) void kv_accum_mfma(const u16* __restrict__ qkv,
                                                     const float* __restrict__ stats,
                                                     float* __restrict__ kvt) {
    const int tc = blockIdx.x;   // 8 chunks of 512 tokens
    const int h  = blockIdx.y;
    const int b  = blockIdx.z;
    __shared__ char ckv[96 * 256];
    __shared__ float ki[48];
    const int tid  = threadIdx.x;
    const int lane = tid & 63, wave = tid >> 6;
    const int fr = lane & 15, kg = lane >> 4;
    if (tid < 48) ki[tid] = 1.0f / stats[b * 768 + 384 + h * 48 + tid];
    __syncthreads();
    f32x4 acc[3][3] = {};
    const u16* kpan = qkv + ((size_t)(b * 3 + 1) * 8 + h) * HPANE;
    const u16* vpan = qkv + ((size_t)(b * 3 + 2) * 8 + h) * HPANE;
    for (int iter = 0; iter < 4; iter++) {
        const size_t tbase = (size_t)(tc * 512 + iter * 128);
        for (int u = tid; u < 1536; u += 256) {
            int p = u / 24, c4 = u % 24;
            int t = p * 2;
            int kpart = (c4 < 12);
            int lch = kpart ? c4 * 4 : (c4 - 12) * 4;       // 0..44
            int ch  = kpart ? lch : (48 + lch);
            const u16* r0 = (kpart ? kpan : vpan) + (tbase + t) * 48 + lch;
            ushort4 a  = *(const ushort4*)r0;
            ushort4 bb = *(const ushort4*)(r0 + 48);
            #pragma unroll
            for (int e = 0; e < 4; e++) {
                u16 ae = ((const u16*)&a)[e], be = ((const u16*)&bb)[e];
                u16 lo, hi;
                if (kpart) {
                    float si = ki[lch + e];
                    lo = f2b(__expf(b2f(ae)) * si);
                    hi = f2b(__expf(b2f(be)) * si);
                } else { lo = ae; hi = be; }
                int che = ch + e;
                int byteoff = che * 256 + ((((t >> 3) ^ (che & 15)) << 4)) + ((t & 7) * 2);
                *(unsigned int*)(ckv + byteoff) = (unsigned int)lo | ((unsigned int)hi << 16);
            }
        }
        __syncthreads();
        const int g0 = wave * 4;  // K-split: wave's 32 tokens (granules of 8)
        bf16x8 afv[3], bfk[3];
        #pragma unroll
        for (int mt = 0; mt < 3; mt++) {
            int chv = 48 + mt * 16 + fr;
            afv[mt] = *(const bf16x8*)(ckv + chv * 256 + (((g0 + kg) ^ (chv & 15)) << 4));
            int chk = mt * 16 + fr;
            bfk[mt] = *(const bf16x8*)(ckv + chk * 256 + (((g0 + kg) ^ (chk & 15)) << 4));
        }
        #pragma unroll
        for (int mt = 0; mt < 3; mt++)
            #pragma unroll
            for (int nt = 0; nt < 3; nt++)
                acc[mt][nt] = __builtin_amdgcn_mfma_f32_16x16x32_bf16(
                                  afv[mt], bfk[nt], acc[mt][nt], 0, 0, 0);
        __syncthreads();
    }
    float* kp = kvt + (size_t)(b * NHEAD + h) * 2304;
    const int orow = kg * 4, ocol = fr;
    #pragma unroll
    for (int mt = 0; mt < 3; mt++)
        #pragma unroll
        for (int nt = 0; nt < 3; nt++)
            #pragma unroll
            for (int j = 0; j < 4; j++)
                atomicAdd(&kp[(mt * 16 + orow + j) * 48 + nt * 16 + ocol], acc[mt][nt][j]);
}

// ----------------------------- KV^T f32 [g][48][48] -> bf16 [g][48][64] zero-padded
__global__ __launch_bounds__(256) void kvt_to_bf16(const float* __restrict__ kvt,
                                                   u16* __restrict__ kvtb) {
    int idx = blockIdx.x * 256 + threadIdx.x;   // 128*48*64
    int g  = idx / 3072;
    int r  = (idx >> 6) % 48;
    int ii = idx & 63;
    float v = (ii < 48) ? kvt[(size_t)g * 2304 + r * 48 + ii] : 0.f;
    kvtb[idx] = f2b(v);
}

// ---------------- attn = (softq @ KV) / (rowsum(softq)+eps) via MFMA, per (tc,h,b)
__global__ __launch_bounds__(256) void attn_mfma(const u16* __restrict__ qkv,
                                                 const float* __restrict__ stats,
                                                 const u16* __restrict__ kvtb,
                                                 u16* __restrict__ attnb) {
    const int tc = blockIdx.x;  // 16 chunks of 256 tokens
    const int h  = blockIdx.y;
    const int b  = blockIdx.z;
    __shared__ u16 obuf[256][50];
    const int tid  = threadIdx.x;
    const int lane = tid & 63, wave = tid >> 6;
    const int fr = lane & 15, kg = lane >> 4;
    const int g = b * NHEAD + h;

    bf16x8 bf[3][2];
    #pragma unroll
    for (int nt = 0; nt < 3; nt++)
        #pragma unroll
        for (int kt = 0; kt < 2; kt++)
            bf[nt][kt] = *(const bf16x8*)(kvtb + (size_t)g * 3072 + (nt * 16 + fr) * 64
                                          + kt * 32 + kg * 8);
    float qi8[2][8];
    #pragma unroll
    for (int kt = 0; kt < 2; kt++) {
        int ch0 = kt * 32 + kg * 8;
        if (ch0 < 48)
            #pragma unroll
            for (int e = 0; e < 8; e++)
                qi8[kt][e] = 1.0f / stats[b * 768 + h * 48 + ch0 + e];
    }

    const u16* qpan = qkv + ((size_t)(b * 3 + 0) * 8 + h) * HPANE;
    f32x4 acc[4][3] = {};
    float den4[4];
    #pragma unroll
    for (int m = 0; m < 4; m++) {
        const u16* qrow = qpan + (size_t)(tc * 256 + wave * 64 + m * 16 + fr) * 48;
        float denp = 0.f;
        bf16x8 af[2];
        #pragma unroll
        for (int kt = 0; kt < 2; kt++) {
            int ch0 = kt * 32 + kg * 8;
            u16x8 av = {};
            if (ch0 < 48) {
                ushort4 a0 = *(const ushort4*)(qrow + ch0);
                ushort4 a1 = *(const ushort4*)(qrow + ch0 + 4);
                #pragma unroll
                for (int e = 0; e < 8; e++) {
                    u16 qv = (e < 4) ? ((const u16*)&a0)[e] : ((const u16*)&a1)[e - 4];
                    float s = __expf(b2f(qv)) * qi8[kt][e];
                    denp += s;
                    av[e] = f2b(s);
                }
            }
            union { u16x8 u; bf16x8 b; } cvt; cvt.u = av;
            af[kt] = cvt.b;
        }
        denp += __shfl_xor(denp, 16);
        denp += __shfl_xor(denp, 32);
        den4[m] = denp + 1e-7f;   // EPS
        #pragma unroll
        for (int nt = 0; nt < 3; nt++)
            #pragma unroll
            for (int kt = 0; kt < 2; kt++)
                acc[m][nt] = __builtin_amdgcn_mfma_f32_16x16x32_bf16(
                                 af[kt], bf[nt][kt], acc[m][nt], 0, 0, 0);
    }
    const int orow = kg * 4, ocol = fr;
    #pragma unroll
    for (int m = 0; m < 4; m++) {
        float rd[4];
        #pragma unroll
        for (int j = 0; j < 4; j++)
            rd[j] = 1.0f / __shfl(den4[m], orow + j);
        #pragma unroll
        for (int nt = 0; nt < 3; nt++)
            #pragma unroll
            for (int j = 0; j < 4; j++)
                obuf[wave * 64 + m * 16 + orow + j][nt * 16 + ocol] =
                    f2b(acc[m][nt][j] * rd[j]);
    }
    __syncthreads();
    u16* ob = attnb + ((size_t)(b * NTOK + tc * 256)) * DMODEL + h * 48;
    for (int u = tid; u < 6144; u += 256) {
        int t = u / 24, c2 = (u % 24) * 2;
        *(ushort2*)(ob + (size_t)t * DMODEL + c2) = *(const ushort2*)&obuf[t][c2];
    }
}

// -----------------------------------------------------------------------------
extern "C" void kernel_launch(void* const* d_in, const int* in_sizes, int n_in,
                              void* d_out, int out_size, void* d_ws, size_t ws_size,
                              hipStream_t stream) {
    const float* x     = (const float*)d_in[0];
    const float* wqkv  = (const float*)d_in[1];
    const float* bqkv  = (const float*)d_in[2];
    const float* wproj = (const float*)d_in[3];
    const float* bproj = (const float*)d_in[4];

    char* ws = (char*)d_ws;
    size_t off = 0;
    auto take = [&](size_t bytes) {
        char* p = ws + off;
        off = (off + bytes + 255) & ~(size_t)255;
        return p;
    };
    u16*   xb    = (u16*)take((size_t)M_ROWS * DMODEL * 2);
    u16*   wqb   = (u16*)take((size_t)QKVC * DMODEL * 2);
    u16*   wpb   = (u16*)take((size_t)DMODEL * DMODEL * 2);
    u16*   qkvb  = (u16*)take((size_t)M_ROWS * QKVC * 2);   // [b][3][h][tok][48]
    float* stats = (float*)take((size_t)BATCH * 768 * sizeof(float));
    float* kvt   = (float*)take((size_t)BATCH * NHEAD * DH * DH * sizeof(float));
    u16*   kvtb  = (u16*)take((size_t)BATCH * NHEAD * DH * 64 * 2);
    u16*   attnb = xb;   // xb dead after GEMM1

    cvt_f32_bf16<<<dim3(M_ROWS * DMODEL / 4 / 256), 256, 0, stream>>>(x, xb, M_ROWS * DMODEL / 4);
    cvt_f32_bf16<<<dim3(QKVC * DMODEL / 4 / 256), 256, 0, stream>>>(wqkv, wqb, QKVC * DMODEL / 4);
    cvt_f32_bf16<<<dim3(DMODEL * DMODEL / 4 / 256), 256, 0, stream>>>(wproj, wpb, DMODEL * DMODEL / 4);

    hipMemsetAsync(stats, 0, (size_t)BATCH * 768 * sizeof(float), stream);
    hipMemsetAsync(kvt, 0, (size_t)BATCH * NHEAD * DH * DH * sizeof(float), stream);

    // QKV = x @ w_qkv^T + b_qkv  -> head panels + fused column sum-exp stats
    gemm_bt<false, true><<<dim3(QKVC / 128, M_ROWS / 128), 256, 0, stream>>>(
        xb, wqb, bqkv, qkvb, stats, M_ROWS, QKVC, DMODEL);

    // KV^T accumulate (f32 atomics) then convert to padded bf16
    kv_accum_mfma<<<dim3(NTOK / 512, NHEAD, BATCH), 256, 0, stream>>>(qkvb, stats, kvt);
    kvt_to_bf16<<<dim3(BATCH * NHEAD * DH * 64 / 256), 256, 0, stream>>>(kvt, kvtb);

    // attn = (softq @ KV) / denom, merged heads
    attn_mfma<<<dim3(16, NHEAD, BATCH), 256, 0, stream>>>(qkvb, stats, kvtb, attnb);

    // out = attn @ w_proj^T + b_proj
    gemm_bt<true, false><<<dim3(DMODEL / 128, M_ROWS / 128), 256, 0, stream>>>(
        attnb, wpb, bproj, d_out, nullptr, M_ROWS, DMODEL, DMODEL);
}